// Round 6
// baseline (907.446 us; speedup 1.0000x reference)
//
#include <hip/hip_runtime.h>

#define DEVFN __device__ __forceinline__

constexpr int C   = 64;
constexpr int Hh  = 160, Ww = 160, HW = Hh * Ww;   // 25600
constexpr int B   = 2;
constexpr int P   = B * HW;                        // 51200
constexpr int NSET = 32;

// NOTE: every kernel carries __launch_bounds__(256). Without it hipcc
// assumes 1024-thread workgroups and caps VGPRs at 64 -> register arrays
// spill to scratch (round-4 profile: k9 VALUBusy 2.5%, 380us).
// NOTE-2 (round 5): a register array indexed by a NON-unrolled loop var is
// demoted to scratch regardless of VGPR budget (k7 round-5: VGPR=56,
// WRITE_SIZE 124MB vs 13MB logical). Keep all array indices static.

// K1: LayerNorm over channels per pixel
__global__ __launch_bounds__(256) void k1_ln1(
        const float* __restrict__ inp, const float* __restrict__ lnw,
        const float* __restrict__ lnb, float* __restrict__ x1) {
    int p = blockIdx.x * 256 + threadIdx.x;
    int b = p / HW, hw = p % HW;
    const float* src = inp + (size_t)b * C * HW + hw;
    float v[64];
    float s = 0.f, s2 = 0.f;
#pragma unroll
    for (int c = 0; c < 64; c++) {
        float f = src[c * HW];
        v[c] = f; s += f; s2 += f * f;
    }
    float mu  = s * (1.f / 64.f);
    float var = fmaxf(s2 * (1.f / 64.f) - mu * mu, 0.f);
    float r   = rsqrtf(var + 1e-6f);
    float* dst = x1 + (size_t)b * C * HW + hw;
#pragma unroll
    for (int c = 0; c < 64; c++)
        dst[c * HW] = (v[c] - mu) * r * lnw[c] + lnb[c];
}

// K2: spatial mean of x1 per (b,c)
__global__ __launch_bounds__(256) void k2_mean(
        const float* __restrict__ x1, float* __restrict__ meanb) {
    int bc = blockIdx.x;                         // 0..127
    const float* src = x1 + (size_t)bc * HW;
    float s = 0.f;
    for (int i = threadIdx.x; i < HW; i += 256) s += src[i];
#pragma unroll
    for (int o = 32; o > 0; o >>= 1) s += __shfl_down(s, o);
    __shared__ float red[4];
    if ((threadIdx.x & 63) == 0) red[threadIdx.x >> 6] = s;
    __syncthreads();
    if (threadIdx.x == 0)
        meanb[bc] = (red[0] + red[1] + red[2] + red[3]) * (1.f / HW);
}

// K3: sca = sca_w @ mean + sca_b   [B,64]
__global__ __launch_bounds__(256) void k3_sca(
        const float* __restrict__ scaw, const float* __restrict__ scab_,
        const float* __restrict__ meanb, float* __restrict__ sca) {
    int t = threadIdx.x;
    if (t >= 128) return;
    int b = t >> 6, c = t & 63;
    float acc = scab_[c];
#pragma unroll
    for (int k = 0; k < 64; k++)
        acc = fmaf(scaw[c * 64 + k], meanb[b * 64 + k], acc);
    sca[t] = acc;
}

// helper for K4: 3x3 grouped conv taps (groups=32, 2 in-ch per out-ch)
template <bool INT_>
DEVFN void att_taps(const float* __restrict__ xb, int h, int w,
                    const float* __restrict__ c2aw, const float* __restrict__ c2ab,
                    float* t) {
#pragma unroll
    for (int o = 0; o < 32; o++) {
        float acc = c2ab[o];
#pragma unroll
        for (int k = 0; k < 2; k++) {
            const float* xc = xb + (size_t)(2 * o + k) * HW;
            const float* wr = c2aw + (o * 2 + k) * 9;
#pragma unroll
            for (int kh = 0; kh < 3; kh++) {
                int y = h + kh - 1;
#pragma unroll
                for (int kw = 0; kw < 3; kw++) {
                    int x = w + kw - 1;
                    if (INT_ || ((unsigned)y < (unsigned)Hh && (unsigned)x < (unsigned)Ww))
                        acc = fmaf(wr[kh * 3 + kw], xc[y * Ww + x], acc);
                }
            }
        }
        t[o] = acc;
    }
}

// K4: att = (1x1 conv(simple_gate(grouped 3x3 conv(x1)))) * attgamma
__global__ __launch_bounds__(256) void k4_att(
        const float* __restrict__ x1, const float* __restrict__ c2aw,
        const float* __restrict__ c2ab, const float* __restrict__ c2bw,
        const float* __restrict__ c2bb, const float* __restrict__ attg,
        float* __restrict__ att) {
    int p = blockIdx.x * 256 + threadIdx.x;
    int b = p / HW, hw = p % HW, h = hw / Ww, w = hw % Ww;
    const float* xb = x1 + (size_t)b * C * HW;
    float t[32];
    bool interior = (h >= 1 && h < Hh - 1 && w >= 1 && w < Ww - 1);
    if (interior) att_taps<true>(xb, h, w, c2aw, c2ab, t);
    else          att_taps<false>(xb, h, w, c2aw, c2ab, t);
    float g[16];
#pragma unroll
    for (int c = 0; c < 16; c++) g[c] = t[c] * t[c + 16];
#pragma unroll 1
    for (int s = 0; s < 32; s++) {
        float acc = c2bb[s];
#pragma unroll
        for (int c = 0; c < 16; c++)
            acc = fmaf(c2bw[s * 16 + c], g[c], acc);
        att[(size_t)(b * NSET + s) * HW + hw] = acc * attg[s];
    }
}

// K5: u1 = 1x1 conv (64x64) of x1
__global__ __launch_bounds__(256) void k5_u1(
        const float* __restrict__ x1, const float* __restrict__ w,
        const float* __restrict__ bias, float* __restrict__ u1) {
    int p = blockIdx.x * 256 + threadIdx.x;
    int b = p / HW, hw = p % HW;
    const float* xc = x1 + (size_t)b * C * HW + hw;
    float xin[64];
#pragma unroll
    for (int c = 0; c < 64; c++) xin[c] = xc[c * HW];
    float* dst = u1 + (size_t)b * C * HW + hw;
#pragma unroll 1
    for (int co = 0; co < 64; co++) {
        float acc = bias[co];
        const float* wr = w + co * 64;
#pragma unroll
        for (int ci = 0; ci < 64; ci++) acc = fmaf(wr[ci], xin[ci], acc);
        dst[co * HW] = acc;
    }
}

// K6: uf = 5x5 grouped conv (groups=16, 4in/4out) of u1, pad=2
__global__ __launch_bounds__(256) void k6_uf(
        const float* __restrict__ u1, const float* __restrict__ w,
        const float* __restrict__ bias, float* __restrict__ uf) {
    int lane = threadIdx.x & 63, wq = threadIdx.x >> 6;
    int p = blockIdx.x * 64 + lane;
    int b = p / HW, hw = p % HW, h = hw / Ww, w_ = hw % Ww;
    bool interior = (h >= 2 && h < Hh - 2 && w_ >= 2 && w_ < Ww - 2);
#pragma unroll 1
    for (int gi = 0; gi < 4; gi++) {
        int g = wq * 4 + gi;
        float acc[4];
#pragma unroll
        for (int o = 0; o < 4; o++) acc[o] = bias[g * 4 + o];
#pragma unroll 1
        for (int cl = 0; cl < 4; cl++) {
            int ci = g * 4 + cl;
            const float* src = u1 + (size_t)(b * C + ci) * HW;
            float tv[25];
            if (interior) {
#pragma unroll
                for (int kh = 0; kh < 5; kh++)
#pragma unroll
                    for (int kw = 0; kw < 5; kw++)
                        tv[kh * 5 + kw] = src[(h + kh - 2) * Ww + (w_ + kw - 2)];
            } else {
#pragma unroll
                for (int kh = 0; kh < 5; kh++) {
                    int y = h + kh - 2;
#pragma unroll
                    for (int kw = 0; kw < 5; kw++) {
                        int x = w_ + kw - 2;
                        tv[kh * 5 + kw] =
                            ((unsigned)y < (unsigned)Hh && (unsigned)x < (unsigned)Ww)
                                ? src[y * Ww + x] : 0.f;
                    }
                }
            }
#pragma unroll
            for (int o = 0; o < 4; o++) {
                const float* wr = w + ((g * 4 + o) * 4 + cl) * 25;
#pragma unroll
                for (int tp = 0; tp < 25; tp++) acc[o] = fmaf(wr[tp], tv[tp], acc[o]);
            }
        }
        float* dst = uf + (size_t)(b * C + g * 4) * HW + hw;
#pragma unroll
        for (int o = 0; o < 4; o++) dst[o * HW] = acc[o];
    }
}

// helper for K7: load one group's 3x3x4 patch into statically-indexed regs
template <bool INT_>
DEVFN void load_patch(const float* __restrict__ uf, int b, int g, int h, int w,
                      float* u) {
#pragma unroll
    for (int cl = 0; cl < 4; cl++) {
        const float* src = uf + (size_t)(b * C + g * 4 + cl) * HW;
#pragma unroll
        for (int kh = 0; kh < 3; kh++) {
            int y = h + kh - 1;
#pragma unroll
            for (int kw = 0; kw < 3; kw++) {
                int x = w + kw - 1;
                if (INT_)
                    u[cl * 9 + kh * 3 + kw] = src[y * Ww + x];
                else
                    u[cl * 9 + kh * 3 + kw] =
                        ((unsigned)y < (unsigned)Hh && (unsigned)x < (unsigned)Ww)
                            ? src[y * Ww + x] : 0.f;
            }
        }
    }
}

// K7: KBA + ga1 + residual uf + sca scaling   -> xmid
// Grid: 200 pixel-blocks x 8 group-pairs; group index from blockIdx ONLY so
// weight addresses are wave-uniform (s_load + SGPR-operand FMA).
// s is the OUTER loop and a[s] is re-loaded from global att each iteration
// (one L2-hit load per ~300 FMAs) -> no dynamically-indexed register array,
// no scratch (round-5 lesson).
__global__ __launch_bounds__(256) void k7_kba(
        const float* __restrict__ att, const float* __restrict__ uf,
        const float* __restrict__ kbw, const float* __restrict__ kbb,
        const float* __restrict__ ga1, const float* __restrict__ sca,
        float* __restrict__ xmid) {
    int blk  = blockIdx.x;                 // 0..1599
    int pblk = blk % 200;
    int gp   = blk / 200;                  // 0..7 -> groups 2*gp, 2*gp+1
    int p  = pblk * 256 + threadIdx.x;
    int b  = p / HW, hw = p % HW, h = hw / Ww, w = hw % Ww;
    int g0 = gp * 2, g1 = g0 + 1;          // uniform

    bool interior = (h >= 1 && h < Hh - 1 && w >= 1 && w < Ww - 1);
    float u0[36], u1v[36];
    if (interior) {
        load_patch<true>(uf, b, g0, h, w, u0);
        load_patch<true>(uf, b, g1, h, w, u1v);
    } else {
        load_patch<false>(uf, b, g0, h, w, u0);
        load_patch<false>(uf, b, g1, h, w, u1v);
    }

    const float* asrc = att + (size_t)b * NSET * HW + hw;
    const float* w0b  = kbw + g0 * 144;    // uniform
    const float* w1b  = kbw + g1 * 144;    // uniform

    float acc0[4] = {0.f, 0.f, 0.f, 0.f}, accb0[4] = {0.f, 0.f, 0.f, 0.f};
    float acc1[4] = {0.f, 0.f, 0.f, 0.f}, accb1[4] = {0.f, 0.f, 0.f, 0.f};

#pragma unroll 1
    for (int s = 0; s < 32; s++) {
        float a = asrc[(size_t)s * HW];            // per-lane, coalesced, L2-hit
        const float* w0 = w0b + (size_t)s * 2304;  // uniform
        const float* w1 = w1b + (size_t)s * 2304;  // uniform
#pragma unroll
        for (int o = 0; o < 4; o++) {
            const float* wo = w0 + o * 36;
            float d = wo[0] * u0[0];
#pragma unroll
            for (int i = 1; i < 36; i++) d = fmaf(wo[i], u0[i], d);
            acc0[o]  = fmaf(a, d, acc0[o]);
            accb0[o] = fmaf(a, kbb[s * 64 + g0 * 4 + o], accb0[o]);
        }
#pragma unroll
        for (int o = 0; o < 4; o++) {
            const float* wo = w1 + o * 36;
            float d = wo[0] * u1v[0];
#pragma unroll
            for (int i = 1; i < 36; i++) d = fmaf(wo[i], u1v[i], d);
            acc1[o]  = fmaf(a, d, acc1[o]);
            accb1[o] = fmaf(a, kbb[s * 64 + g1 * 4 + o], accb1[o]);
        }
    }

    float scb = sca[b * 64 + g0 * 4];  // per-channel below; load individually
#pragma unroll
    for (int o = 0; o < 4; o++) {
        int co = g0 * 4 + o;
        float outv = (acc0[o] + accb0[o]) * ga1[co] + u0[o * 9 + 4];
        outv *= sca[b * 64 + co];
        xmid[(size_t)(b * C + co) * HW + hw] = outv;
    }
#pragma unroll
    for (int o = 0; o < 4; o++) {
        int co = g1 * 4 + o;
        float outv = (acc1[o] + accb1[o]) * ga1[co] + u1v[o * 9 + 4];
        outv *= sca[b * 64 + co];
        xmid[(size_t)(b * C + co) * HW + hw] = outv;
    }
    (void)scb;
}

// K8: conv3 (1x1 64x64) + residual:  y = inp + conv3(xmid)*beta
__global__ __launch_bounds__(256) void k8_conv3(
        const float* __restrict__ xmid, const float* __restrict__ inp,
        const float* __restrict__ w, const float* __restrict__ bias,
        const float* __restrict__ beta, float* __restrict__ y) {
    int p = blockIdx.x * 256 + threadIdx.x;
    int b = p / HW, hw = p % HW;
    const float* xc = xmid + (size_t)b * C * HW + hw;
    float xin[64];
#pragma unroll
    for (int c = 0; c < 64; c++) xin[c] = xc[c * HW];
#pragma unroll 1
    for (int co = 0; co < 64; co++) {
        float acc = bias[co];
        const float* wr = w + co * 64;
#pragma unroll
        for (int ci = 0; ci < 64; ci++) acc = fmaf(wr[ci], xin[ci], acc);
        float inv = inp[(size_t)(b * C + co) * HW + hw];
        y[(size_t)(b * C + co) * HW + hw] = inv + acc * beta[co];
    }
}

// K9: FFN: LN2 -> conv4 (128) -> gate -> conv5 (64) -> + y*gamma
__global__ __launch_bounds__(256) void k9_ffn(
        const float* __restrict__ y, const float* __restrict__ lnw,
        const float* __restrict__ lnb, const float* __restrict__ w4,
        const float* __restrict__ b4, const float* __restrict__ w5,
        const float* __restrict__ b5, const float* __restrict__ gamma,
        float* __restrict__ out) {
    int p = blockIdx.x * 256 + threadIdx.x;
    int b = p / HW, hw = p % HW;
    const float* yc = y + (size_t)b * C * HW + hw;
    float v[64];
    float s = 0.f, s2 = 0.f;
#pragma unroll
    for (int c = 0; c < 64; c++) {
        float f = yc[c * HW];
        v[c] = f; s += f; s2 += f * f;
    }
    float mu  = s * (1.f / 64.f);
    float var = fmaxf(s2 * (1.f / 64.f) - mu * mu, 0.f);
    float r   = rsqrtf(var + 1e-6f);
#pragma unroll
    for (int c = 0; c < 64; c++)
        v[c] = (v[c] - mu) * r * lnw[c] + lnb[c];

    float acc[64];
#pragma unroll
    for (int co = 0; co < 64; co++) acc[co] = b5[co];

#pragma unroll 1
    for (int j = 0; j < 64; j++) {
        float t1 = b4[j];
        float t2 = b4[64 + j];
        const float* w1 = w4 + j * 64;
        const float* w2 = w1 + 64 * 64;
#pragma unroll
        for (int ci = 0; ci < 64; ci++) {
            t1 = fmaf(w1[ci], v[ci], t1);
            t2 = fmaf(w2[ci], v[ci], t2);
        }
        float gj = t1 * t2;
#pragma unroll
        for (int co = 0; co < 64; co++)
            acc[co] = fmaf(w5[co * 64 + j], gj, acc[co]);
    }
#pragma unroll
    for (int co = 0; co < 64; co++) {
        float o = yc[co * HW] + acc[co] * gamma[co];
        out[(size_t)(b * C + co) * HW + hw] = o;
    }
}

extern "C" void kernel_launch(void* const* d_in, const int* in_sizes, int n_in,
                              void* d_out, int out_size, void* d_ws, size_t ws_size,
                              hipStream_t stream) {
    (void)in_sizes; (void)n_in; (void)out_size; (void)ws_size;

    const float* inp     = (const float*)d_in[0];
    const float* ln1_w   = (const float*)d_in[1];
    const float* ln1_b   = (const float*)d_in[2];
    const float* ln2_w   = (const float*)d_in[3];
    const float* ln2_b   = (const float*)d_in[4];
    const float* sca_w   = (const float*)d_in[5];
    const float* sca_b   = (const float*)d_in[6];
    const float* c11a_w  = (const float*)d_in[7];
    const float* c11a_b  = (const float*)d_in[8];
    const float* c11b_w  = (const float*)d_in[9];
    const float* c11b_b  = (const float*)d_in[10];
    const float* c2a_w   = (const float*)d_in[11];
    const float* c2a_b   = (const float*)d_in[12];
    const float* c2b_w   = (const float*)d_in[13];
    const float* c2b_b   = (const float*)d_in[14];
    const float* conv3_w = (const float*)d_in[15];
    const float* conv3_b = (const float*)d_in[16];
    const float* conv4_w = (const float*)d_in[17];
    const float* conv4_b = (const float*)d_in[18];
    const float* conv5_w = (const float*)d_in[19];
    const float* conv5_b = (const float*)d_in[20];
    const float* kb_w    = (const float*)d_in[21];
    const float* kb_b    = (const float*)d_in[22];
    const float* ga1     = (const float*)d_in[23];
    const float* attg    = (const float*)d_in[24];
    const float* beta    = (const float*)d_in[25];
    const float* gamma   = (const float*)d_in[26];

    // ---- ws arena (~33 MB) ----
    char* ws = (char*)d_ws;
    size_t off = 0;
    auto alloc = [&](size_t bytes) {
        void* r = ws + off;
        off += (bytes + 255) & ~(size_t)255;
        return r;
    };
    float* meanb = (float*)alloc(128 * 4);
    float* scab  = (float*)alloc(128 * 4);
    float* x1    = (float*)alloc((size_t)P * 64 * 4);   // 13.1 MB
    float* attb  = (float*)alloc((size_t)P * 32 * 4);   // 6.55 MB
    float* u1    = (float*)alloc((size_t)P * 64 * 4);   // 13.1 MB
    float* ufb   = x1;   // x1 dead after K5
    float* xmid  = u1;   // u1 dead after K6
    float* yb    = x1;   // ufb dead after K7

    k1_ln1   <<<P / 256, 256, 0, stream>>>(inp, ln1_w, ln1_b, x1);
    k2_mean  <<<B * C, 256, 0, stream>>>(x1, meanb);
    k3_sca   <<<1, 128, 0, stream>>>(sca_w, sca_b, meanb, scab);
    k4_att   <<<P / 256, 256, 0, stream>>>(x1, c2a_w, c2a_b, c2b_w, c2b_b, attg, attb);
    k5_u1    <<<P / 256, 256, 0, stream>>>(x1, c11a_w, c11a_b, u1);
    k6_uf    <<<P / 64, 256, 0, stream>>>(u1, c11b_w, c11b_b, ufb);
    k7_kba   <<<1600, 256, 0, stream>>>(attb, ufb, kb_w, kb_b, ga1, scab, xmid);
    k8_conv3 <<<P / 256, 256, 0, stream>>>(xmid, inp, conv3_w, conv3_b, beta, yb);
    k9_ffn   <<<P / 256, 256, 0, stream>>>(yb, ln2_w, ln2_b, conv4_w, conv4_b,
                                           conv5_w, conv5_b, gamma, (float*)d_out);
}

// Round 7
// 810.932 us; speedup vs baseline: 1.1190x; 1.1190x over previous
//
#include <hip/hip_runtime.h>

#define DEVFN __device__ __forceinline__

constexpr int C   = 64;
constexpr int Hh  = 160, Ww = 160, HW = Hh * Ww;   // 25600
constexpr int B   = 2;
constexpr int P   = B * HW;                        // 51200
constexpr int NSET = 32;

// NOTE: every kernel carries __launch_bounds__(256). Without it hipcc
// assumes 1024-thread workgroups and caps VGPRs at 64 -> register arrays
// spill to scratch (round-4 profile: k9 VALUBusy 2.5%, 380us).
// NOTE-2 (round 5): a register array indexed by a NON-unrolled loop var is
// demoted to scratch regardless of VGPR budget. Keep all array indices static.
// NOTE-3 (round 6): uniform weights streamed through SGPRs cap at ~36-48
// floats/iter (s_load chunk + waitcnt serialization: VALUBusy 26%). For
// >100 uniform floats per iteration, stage in LDS and ds_read (broadcast).

// K1: LayerNorm over channels per pixel
__global__ __launch_bounds__(256) void k1_ln1(
        const float* __restrict__ inp, const float* __restrict__ lnw,
        const float* __restrict__ lnb, float* __restrict__ x1) {
    int p = blockIdx.x * 256 + threadIdx.x;
    int b = p / HW, hw = p % HW;
    const float* src = inp + (size_t)b * C * HW + hw;
    float v[64];
    float s = 0.f, s2 = 0.f;
#pragma unroll
    for (int c = 0; c < 64; c++) {
        float f = src[c * HW];
        v[c] = f; s += f; s2 += f * f;
    }
    float mu  = s * (1.f / 64.f);
    float var = fmaxf(s2 * (1.f / 64.f) - mu * mu, 0.f);
    float r   = rsqrtf(var + 1e-6f);
    float* dst = x1 + (size_t)b * C * HW + hw;
#pragma unroll
    for (int c = 0; c < 64; c++)
        dst[c * HW] = (v[c] - mu) * r * lnw[c] + lnb[c];
}

// K2: spatial mean of x1 per (b,c)
__global__ __launch_bounds__(256) void k2_mean(
        const float* __restrict__ x1, float* __restrict__ meanb) {
    int bc = blockIdx.x;                         // 0..127
    const float* src = x1 + (size_t)bc * HW;
    float s = 0.f;
    for (int i = threadIdx.x; i < HW; i += 256) s += src[i];
#pragma unroll
    for (int o = 32; o > 0; o >>= 1) s += __shfl_down(s, o);
    __shared__ float red[4];
    if ((threadIdx.x & 63) == 0) red[threadIdx.x >> 6] = s;
    __syncthreads();
    if (threadIdx.x == 0)
        meanb[bc] = (red[0] + red[1] + red[2] + red[3]) * (1.f / HW);
}

// K3: sca = sca_w @ mean + sca_b   [B,64]
__global__ __launch_bounds__(256) void k3_sca(
        const float* __restrict__ scaw, const float* __restrict__ scab_,
        const float* __restrict__ meanb, float* __restrict__ sca) {
    int t = threadIdx.x;
    if (t >= 128) return;
    int b = t >> 6, c = t & 63;
    float acc = scab_[c];
#pragma unroll
    for (int k = 0; k < 64; k++)
        acc = fmaf(scaw[c * 64 + k], meanb[b * 64 + k], acc);
    sca[t] = acc;
}

// helper for K4: 3x3 grouped conv taps (groups=32, 2 in-ch per out-ch)
template <bool INT_>
DEVFN void att_taps(const float* __restrict__ xb, int h, int w,
                    const float* __restrict__ c2aw, const float* __restrict__ c2ab,
                    float* t) {
#pragma unroll
    for (int o = 0; o < 32; o++) {
        float acc = c2ab[o];
#pragma unroll
        for (int k = 0; k < 2; k++) {
            const float* xc = xb + (size_t)(2 * o + k) * HW;
            const float* wr = c2aw + (o * 2 + k) * 9;
#pragma unroll
            for (int kh = 0; kh < 3; kh++) {
                int y = h + kh - 1;
#pragma unroll
                for (int kw = 0; kw < 3; kw++) {
                    int x = w + kw - 1;
                    if (INT_ || ((unsigned)y < (unsigned)Hh && (unsigned)x < (unsigned)Ww))
                        acc = fmaf(wr[kh * 3 + kw], xc[y * Ww + x], acc);
                }
            }
        }
        t[o] = acc;
    }
}

// K4: att = (1x1 conv(simple_gate(grouped 3x3 conv(x1)))) * attgamma
__global__ __launch_bounds__(256) void k4_att(
        const float* __restrict__ x1, const float* __restrict__ c2aw,
        const float* __restrict__ c2ab, const float* __restrict__ c2bw,
        const float* __restrict__ c2bb, const float* __restrict__ attg,
        float* __restrict__ att) {
    int p = blockIdx.x * 256 + threadIdx.x;
    int b = p / HW, hw = p % HW, h = hw / Ww, w = hw % Ww;
    const float* xb = x1 + (size_t)b * C * HW;
    float t[32];
    bool interior = (h >= 1 && h < Hh - 1 && w >= 1 && w < Ww - 1);
    if (interior) att_taps<true>(xb, h, w, c2aw, c2ab, t);
    else          att_taps<false>(xb, h, w, c2aw, c2ab, t);
    float g[16];
#pragma unroll
    for (int c = 0; c < 16; c++) g[c] = t[c] * t[c + 16];
#pragma unroll 1
    for (int s = 0; s < 32; s++) {
        float acc = c2bb[s];
#pragma unroll
        for (int c = 0; c < 16; c++)
            acc = fmaf(c2bw[s * 16 + c], g[c], acc);
        att[(size_t)(b * NSET + s) * HW + hw] = acc * attg[s];
    }
}

// K5: u1 = 1x1 conv (64x64) of x1
__global__ __launch_bounds__(256) void k5_u1(
        const float* __restrict__ x1, const float* __restrict__ w,
        const float* __restrict__ bias, float* __restrict__ u1) {
    int p = blockIdx.x * 256 + threadIdx.x;
    int b = p / HW, hw = p % HW;
    const float* xc = x1 + (size_t)b * C * HW + hw;
    float xin[64];
#pragma unroll
    for (int c = 0; c < 64; c++) xin[c] = xc[c * HW];
    float* dst = u1 + (size_t)b * C * HW + hw;
#pragma unroll 1
    for (int co = 0; co < 64; co++) {
        float acc = bias[co];
        const float* wr = w + co * 64;
#pragma unroll
        for (int ci = 0; ci < 64; ci++) acc = fmaf(wr[ci], xin[ci], acc);
        dst[co * HW] = acc;
    }
}

// K6: uf = 5x5 grouped conv (groups=16, 4in/4out) of u1, pad=2
__global__ __launch_bounds__(256) void k6_uf(
        const float* __restrict__ u1, const float* __restrict__ w,
        const float* __restrict__ bias, float* __restrict__ uf) {
    int lane = threadIdx.x & 63, wq = threadIdx.x >> 6;
    int p = blockIdx.x * 64 + lane;
    int b = p / HW, hw = p % HW, h = hw / Ww, w_ = hw % Ww;
    bool interior = (h >= 2 && h < Hh - 2 && w_ >= 2 && w_ < Ww - 2);
#pragma unroll 1
    for (int gi = 0; gi < 4; gi++) {
        int g = wq * 4 + gi;
        float acc[4];
#pragma unroll
        for (int o = 0; o < 4; o++) acc[o] = bias[g * 4 + o];
#pragma unroll 1
        for (int cl = 0; cl < 4; cl++) {
            int ci = g * 4 + cl;
            const float* src = u1 + (size_t)(b * C + ci) * HW;
            float tv[25];
            if (interior) {
#pragma unroll
                for (int kh = 0; kh < 5; kh++)
#pragma unroll
                    for (int kw = 0; kw < 5; kw++)
                        tv[kh * 5 + kw] = src[(h + kh - 2) * Ww + (w_ + kw - 2)];
            } else {
#pragma unroll
                for (int kh = 0; kh < 5; kh++) {
                    int y = h + kh - 2;
#pragma unroll
                    for (int kw = 0; kw < 5; kw++) {
                        int x = w_ + kw - 2;
                        tv[kh * 5 + kw] =
                            ((unsigned)y < (unsigned)Hh && (unsigned)x < (unsigned)Ww)
                                ? src[y * Ww + x] : 0.f;
                    }
                }
            }
#pragma unroll
            for (int o = 0; o < 4; o++) {
                const float* wr = w + ((g * 4 + o) * 4 + cl) * 25;
#pragma unroll
                for (int tp = 0; tp < 25; tp++) acc[o] = fmaf(wr[tp], tv[tp], acc[o]);
            }
        }
        float* dst = uf + (size_t)(b * C + g * 4) * HW + hw;
#pragma unroll
        for (int o = 0; o < 4; o++) dst[o * HW] = acc[o];
    }
}

// helper for K7: load one group's 3x3x4 patch into statically-indexed regs
template <bool INT_>
DEVFN void load_patch(const float* __restrict__ uf, int b, int g, int h, int w,
                      float* u) {
#pragma unroll
    for (int cl = 0; cl < 4; cl++) {
        const float* src = uf + (size_t)(b * C + g * 4 + cl) * HW;
#pragma unroll
        for (int kh = 0; kh < 3; kh++) {
            int y = h + kh - 1;
#pragma unroll
            for (int kw = 0; kw < 3; kw++) {
                int x = w + kw - 1;
                if (INT_)
                    u[cl * 9 + kh * 3 + kw] = src[y * Ww + x];
                else
                    u[cl * 9 + kh * 3 + kw] =
                        ((unsigned)y < (unsigned)Hh && (unsigned)x < (unsigned)Ww)
                            ? src[y * Ww + x] : 0.f;
            }
        }
    }
}

// K7: KBA + ga1 + residual uf + sca scaling -> xmid
// Block = 512 pixels x 1 group (grid 100 x 16); thread = 2 pixels.
// Weights for the group (W[s][o][i] 4608f + kbb[s][o] 128f = 18.9KB) staged
// in LDS once; s-loop reads them via broadcast ds_read_b128 (no SGPR limit,
// round-6 lesson). All register arrays statically indexed (round-5 lesson).
// Note 512 divides HW -> b is block-uniform.
__global__ __launch_bounds__(256) void k7_kba(
        const float* __restrict__ att, const float* __restrict__ uf,
        const float* __restrict__ kbw, const float* __restrict__ kbb,
        const float* __restrict__ ga1, const float* __restrict__ sca,
        float* __restrict__ xmid) {
    __shared__ float wsm[4608 + 128];
    int bi  = blockIdx.x;              // 0..1599
    int g   = bi / 100;                // 0..15 (uniform)
    int pb  = bi % 100;
    int tid = threadIdx.x;

    // stage W[g]: global kbw[s*2304 + g*144 + r] -> wsm[s*144 + r]
    for (int e = tid; e < 4608; e += 256) {
        int s = e / 144, r = e - s * 144;
        wsm[e] = kbw[(size_t)s * 2304 + g * 144 + r];
    }
    // stage kbb[g]: kbb[s*64 + g*4 + o] -> wsm[4608 + s*4 + o]
    if (tid < 128) {
        int s = tid >> 2, o = tid & 3;
        wsm[4608 + tid] = kbb[s * 64 + g * 4 + o];
    }
    __syncthreads();

    int pA = pb * 512 + tid;
    int pB = pA + 256;
    int b  = pA / HW;                          // uniform (512 | HW)
    int hwA = pA - b * HW, hwB = pB - b * HW;
    int hA = hwA / Ww, wA = hwA - hA * Ww;
    int hB = hwB / Ww, wB = hwB - hB * Ww;

    float uA[36], uB[36];
    bool intA = (hA >= 1 && hA < Hh - 1 && wA >= 1 && wA < Ww - 1);
    bool intB = (hB >= 1 && hB < Hh - 1 && wB >= 1 && wB < Ww - 1);
    if (intA) load_patch<true>(uf, b, g, hA, wA, uA);
    else      load_patch<false>(uf, b, g, hA, wA, uA);
    if (intB) load_patch<true>(uf, b, g, hB, wB, uB);
    else      load_patch<false>(uf, b, g, hB, wB, uB);

    const float* aA = att + (size_t)b * NSET * HW + hwA;
    const float* aB = att + (size_t)b * NSET * HW + hwB;

    float acc0[4] = {0.f, 0.f, 0.f, 0.f}, accb0[4] = {0.f, 0.f, 0.f, 0.f};
    float acc1[4] = {0.f, 0.f, 0.f, 0.f}, accb1[4] = {0.f, 0.f, 0.f, 0.f};

#pragma unroll 1
    for (int s = 0; s < 32; s++) {
        float a0 = aA[(size_t)s * HW];
        float a1 = aB[(size_t)s * HW];
        const float* wp = &wsm[s * 144];
#pragma unroll
        for (int o = 0; o < 4; o++) {
            const float* wo = wp + o * 36;
            float d0 = wo[0] * uA[0];
            float d1 = wo[0] * uB[0];
#pragma unroll
            for (int i = 1; i < 36; i++) {
                d0 = fmaf(wo[i], uA[i], d0);
                d1 = fmaf(wo[i], uB[i], d1);
            }
            acc0[o] = fmaf(a0, d0, acc0[o]);
            acc1[o] = fmaf(a1, d1, acc1[o]);
        }
        const float* kbp = &wsm[4608 + s * 4];
#pragma unroll
        for (int o = 0; o < 4; o++) {
            accb0[o] = fmaf(a0, kbp[o], accb0[o]);
            accb1[o] = fmaf(a1, kbp[o], accb1[o]);
        }
    }

#pragma unroll
    for (int o = 0; o < 4; o++) {
        int co = g * 4 + o;                    // uniform
        float ga = ga1[co];
        float sc = sca[b * 64 + co];
        float ovA = ((acc0[o] + accb0[o]) * ga + uA[o * 9 + 4]) * sc;
        float ovB = ((acc1[o] + accb1[o]) * ga + uB[o * 9 + 4]) * sc;
        xmid[(size_t)(b * C + co) * HW + hwA] = ovA;
        xmid[(size_t)(b * C + co) * HW + hwB] = ovB;
    }
}

// K8: conv3 (1x1 64x64) + residual:  y = inp + conv3(xmid)*beta
__global__ __launch_bounds__(256) void k8_conv3(
        const float* __restrict__ xmid, const float* __restrict__ inp,
        const float* __restrict__ w, const float* __restrict__ bias,
        const float* __restrict__ beta, float* __restrict__ y) {
    int p = blockIdx.x * 256 + threadIdx.x;
    int b = p / HW, hw = p % HW;
    const float* xc = xmid + (size_t)b * C * HW + hw;
    float xin[64];
#pragma unroll
    for (int c = 0; c < 64; c++) xin[c] = xc[c * HW];
#pragma unroll 1
    for (int co = 0; co < 64; co++) {
        float acc = bias[co];
        const float* wr = w + co * 64;
#pragma unroll
        for (int ci = 0; ci < 64; ci++) acc = fmaf(wr[ci], xin[ci], acc);
        float inv = inp[(size_t)(b * C + co) * HW + hw];
        y[(size_t)(b * C + co) * HW + hw] = inv + acc * beta[co];
    }
}

// K9: FFN: LN2 -> conv4 (128) -> gate -> conv5 (64) -> + y*gamma
__global__ __launch_bounds__(256) void k9_ffn(
        const float* __restrict__ y, const float* __restrict__ lnw,
        const float* __restrict__ lnb, const float* __restrict__ w4,
        const float* __restrict__ b4, const float* __restrict__ w5,
        const float* __restrict__ b5, const float* __restrict__ gamma,
        float* __restrict__ out) {
    int p = blockIdx.x * 256 + threadIdx.x;
    int b = p / HW, hw = p % HW;
    const float* yc = y + (size_t)b * C * HW + hw;
    float v[64];
    float s = 0.f, s2 = 0.f;
#pragma unroll
    for (int c = 0; c < 64; c++) {
        float f = yc[c * HW];
        v[c] = f; s += f; s2 += f * f;
    }
    float mu  = s * (1.f / 64.f);
    float var = fmaxf(s2 * (1.f / 64.f) - mu * mu, 0.f);
    float r   = rsqrtf(var + 1e-6f);
#pragma unroll
    for (int c = 0; c < 64; c++)
        v[c] = (v[c] - mu) * r * lnw[c] + lnb[c];

    float acc[64];
#pragma unroll
    for (int co = 0; co < 64; co++) acc[co] = b5[co];

#pragma unroll 1
    for (int j = 0; j < 64; j++) {
        float t1 = b4[j];
        float t2 = b4[64 + j];
        const float* w1 = w4 + j * 64;
        const float* w2 = w1 + 64 * 64;
#pragma unroll
        for (int ci = 0; ci < 64; ci++) {
            t1 = fmaf(w1[ci], v[ci], t1);
            t2 = fmaf(w2[ci], v[ci], t2);
        }
        float gj = t1 * t2;
#pragma unroll
        for (int co = 0; co < 64; co++)
            acc[co] = fmaf(w5[co * 64 + j], gj, acc[co]);
    }
#pragma unroll
    for (int co = 0; co < 64; co++) {
        float o = yc[co * HW] + acc[co] * gamma[co];
        out[(size_t)(b * C + co) * HW + hw] = o;
    }
}

extern "C" void kernel_launch(void* const* d_in, const int* in_sizes, int n_in,
                              void* d_out, int out_size, void* d_ws, size_t ws_size,
                              hipStream_t stream) {
    (void)in_sizes; (void)n_in; (void)out_size; (void)ws_size;

    const float* inp     = (const float*)d_in[0];
    const float* ln1_w   = (const float*)d_in[1];
    const float* ln1_b   = (const float*)d_in[2];
    const float* ln2_w   = (const float*)d_in[3];
    const float* ln2_b   = (const float*)d_in[4];
    const float* sca_w   = (const float*)d_in[5];
    const float* sca_b   = (const float*)d_in[6];
    const float* c11a_w  = (const float*)d_in[7];
    const float* c11a_b  = (const float*)d_in[8];
    const float* c11b_w  = (const float*)d_in[9];
    const float* c11b_b  = (const float*)d_in[10];
    const float* c2a_w   = (const float*)d_in[11];
    const float* c2a_b   = (const float*)d_in[12];
    const float* c2b_w   = (const float*)d_in[13];
    const float* c2b_b   = (const float*)d_in[14];
    const float* conv3_w = (const float*)d_in[15];
    const float* conv3_b = (const float*)d_in[16];
    const float* conv4_w = (const float*)d_in[17];
    const float* conv4_b = (const float*)d_in[18];
    const float* conv5_w = (const float*)d_in[19];
    const float* conv5_b = (const float*)d_in[20];
    const float* kb_w    = (const float*)d_in[21];
    const float* kb_b    = (const float*)d_in[22];
    const float* ga1     = (const float*)d_in[23];
    const float* attg    = (const float*)d_in[24];
    const float* beta    = (const float*)d_in[25];
    const float* gamma   = (const float*)d_in[26];

    // ---- ws arena (~33 MB) ----
    char* ws = (char*)d_ws;
    size_t off = 0;
    auto alloc = [&](size_t bytes) {
        void* r = ws + off;
        off += (bytes + 255) & ~(size_t)255;
        return r;
    };
    float* meanb = (float*)alloc(128 * 4);
    float* scab  = (float*)alloc(128 * 4);
    float* x1    = (float*)alloc((size_t)P * 64 * 4);   // 13.1 MB
    float* attb  = (float*)alloc((size_t)P * 32 * 4);   // 6.55 MB
    float* u1    = (float*)alloc((size_t)P * 64 * 4);   // 13.1 MB
    float* ufb   = x1;   // x1 dead after K5
    float* xmid  = u1;   // u1 dead after K6
    float* yb    = x1;   // ufb dead after K7

    k1_ln1   <<<P / 256, 256, 0, stream>>>(inp, ln1_w, ln1_b, x1);
    k2_mean  <<<B * C, 256, 0, stream>>>(x1, meanb);
    k3_sca   <<<1, 128, 0, stream>>>(sca_w, sca_b, meanb, scab);
    k4_att   <<<P / 256, 256, 0, stream>>>(x1, c2a_w, c2a_b, c2b_w, c2b_b, attg, attb);
    k5_u1    <<<P / 256, 256, 0, stream>>>(x1, c11a_w, c11a_b, u1);
    k6_uf    <<<P / 64, 256, 0, stream>>>(u1, c11b_w, c11b_b, ufb);
    k7_kba   <<<1600, 256, 0, stream>>>(attb, ufb, kb_w, kb_b, ga1, scab, xmid);
    k8_conv3 <<<P / 256, 256, 0, stream>>>(xmid, inp, conv3_w, conv3_b, beta, yb);
    k9_ffn   <<<P / 256, 256, 0, stream>>>(yb, ln2_w, ln2_b, conv4_w, conv4_b,
                                           conv5_w, conv5_b, gamma, (float*)d_out);
}

// Round 8
// 722.400 us; speedup vs baseline: 1.2562x; 1.1226x over previous
//
#include <hip/hip_runtime.h>

#define DEVFN __device__ __forceinline__

constexpr int C   = 64;
constexpr int Hh  = 160, Ww = 160, HW = Hh * Ww;   // 25600
constexpr int B   = 2;
constexpr int P   = B * HW;                        // 51200
constexpr int NSET = 32;

// NOTE: every kernel carries __launch_bounds__(256); without it hipcc caps
// VGPRs at 64 and register arrays spill (round 4).
// NOTE-2 (round 5): register arrays must be statically indexed everywhere or
// they demote to scratch.
// NOTE-3 (round 6): >~48 uniform floats per loop iteration cannot stream
// through SGPRs (s_load+waitcnt serializes); stage them in LDS.
// NOTE-4 (round 7): a single serial FMA dot-chain holds a SIMD at ~50%;
// provide >=4 independent chains per loop body.

// K1: LayerNorm over channels per pixel
__global__ __launch_bounds__(256) void k1_ln1(
        const float* __restrict__ inp, const float* __restrict__ lnw,
        const float* __restrict__ lnb, float* __restrict__ x1) {
    int p = blockIdx.x * 256 + threadIdx.x;
    int b = p / HW, hw = p % HW;
    const float* src = inp + (size_t)b * C * HW + hw;
    float v[64];
    float s = 0.f, s2 = 0.f;
#pragma unroll
    for (int c = 0; c < 64; c++) {
        float f = src[c * HW];
        v[c] = f; s += f; s2 += f * f;
    }
    float mu  = s * (1.f / 64.f);
    float var = fmaxf(s2 * (1.f / 64.f) - mu * mu, 0.f);
    float r   = rsqrtf(var + 1e-6f);
    float* dst = x1 + (size_t)b * C * HW + hw;
#pragma unroll
    for (int c = 0; c < 64; c++)
        dst[c * HW] = (v[c] - mu) * r * lnw[c] + lnb[c];
}

// K2: spatial mean of x1 per (b,c)
__global__ __launch_bounds__(256) void k2_mean(
        const float* __restrict__ x1, float* __restrict__ meanb) {
    int bc = blockIdx.x;                         // 0..127
    const float* src = x1 + (size_t)bc * HW;
    float s = 0.f;
    for (int i = threadIdx.x; i < HW; i += 256) s += src[i];
#pragma unroll
    for (int o = 32; o > 0; o >>= 1) s += __shfl_down(s, o);
    __shared__ float red[4];
    if ((threadIdx.x & 63) == 0) red[threadIdx.x >> 6] = s;
    __syncthreads();
    if (threadIdx.x == 0)
        meanb[bc] = (red[0] + red[1] + red[2] + red[3]) * (1.f / HW);
}

// K3: sca = sca_w @ mean + sca_b   [B,64]
__global__ __launch_bounds__(256) void k3_sca(
        const float* __restrict__ scaw, const float* __restrict__ scab_,
        const float* __restrict__ meanb, float* __restrict__ sca) {
    int t = threadIdx.x;
    if (t >= 128) return;
    int b = t >> 6, c = t & 63;
    float acc = scab_[c];
#pragma unroll
    for (int k = 0; k < 64; k++)
        acc = fmaf(scaw[c * 64 + k], meanb[b * 64 + k], acc);
    sca[t] = acc;
}

// helper: 3x3 grouped conv taps (groups=32, 2 in-ch per out-ch)
template <bool INT_>
DEVFN void att_taps(const float* __restrict__ xb, int h, int w,
                    const float* c2aw, const float* c2ab, float* t) {
#pragma unroll
    for (int o = 0; o < 32; o++) {
        float acc = c2ab[o];
#pragma unroll
        for (int k = 0; k < 2; k++) {
            const float* xc = xb + (size_t)(2 * o + k) * HW;
            const float* wr = c2aw + (o * 2 + k) * 9;
#pragma unroll
            for (int kh = 0; kh < 3; kh++) {
                int y = h + kh - 1;
#pragma unroll
                for (int kw = 0; kw < 3; kw++) {
                    int x = w + kw - 1;
                    if (INT_ || ((unsigned)y < (unsigned)Hh && (unsigned)x < (unsigned)Ww))
                        acc = fmaf(wr[kh * 3 + kw], xc[y * Ww + x], acc);
                }
            }
        }
        t[o] = acc;
    }
}

// K45: fused k4 (att) + k5 (u1) — both read x1 at the same pixel.
// All weights staged in LDS (NOTE-3); c11a stored TRANSPOSED so the u1 part
// runs ci-outer with 64 independent accumulator chains (NOTE-4).
// LDS layout (floats): A11T[0,4096) A11b[4096,4160) C2A[4160,4736)
// C2Ab[4736,4768) C2B[4768,5280) C2Bb[5280,5312) ATTG[5312,5344)
__global__ __launch_bounds__(256) void k45_attu(
        const float* __restrict__ x1, const float* __restrict__ c2aw,
        const float* __restrict__ c2ab, const float* __restrict__ c2bw,
        const float* __restrict__ c2bb, const float* __restrict__ attg,
        const float* __restrict__ c11aw, const float* __restrict__ c11ab,
        float* __restrict__ att, float* __restrict__ u1) {
    __shared__ float Wsm[5344];
    int tid = threadIdx.x;
    for (int e = tid; e < 5344; e += 256) {
        float v;
        if (e < 4096)      v = c11aw[(e & 63) * 64 + (e >> 6)];  // A11T[ci*64+co]
        else if (e < 4160) v = c11ab[e - 4096];
        else if (e < 4736) v = c2aw[e - 4160];
        else if (e < 4768) v = c2ab[e - 4736];
        else if (e < 5280) v = c2bw[e - 4768];
        else if (e < 5312) v = c2bb[e - 5280];
        else               v = attg[e - 5312];
        Wsm[e] = v;
    }
    __syncthreads();

    int p = blockIdx.x * 256 + tid;
    int b = p / HW, hw = p % HW, h = hw / Ww, w = hw % Ww;
    const float* xb = x1 + (size_t)b * C * HW;

    // ---- k4 part ----
    float t[32];
    bool interior = (h >= 1 && h < Hh - 1 && w >= 1 && w < Ww - 1);
    if (interior) att_taps<true>(xb, h, w, &Wsm[4160], &Wsm[4736], t);
    else          att_taps<false>(xb, h, w, &Wsm[4160], &Wsm[4736], t);
    float g[16];
#pragma unroll
    for (int c = 0; c < 16; c++) g[c] = t[c] * t[c + 16];
    float* adst = att + (size_t)b * NSET * HW + hw;
#pragma unroll 1
    for (int s = 0; s < 32; s++) {
        float acc = Wsm[5280 + s];
        const float* wr = &Wsm[4768 + s * 16];
#pragma unroll
        for (int c = 0; c < 16; c++) acc = fmaf(wr[c], g[c], acc);
        adst[(size_t)s * HW] = acc * Wsm[5312 + s];
    }

    // ---- k5 part: ci-outer, transposed weights, 64 chains ----
    float ua[64];
#pragma unroll
    for (int co = 0; co < 64; co++) ua[co] = Wsm[4096 + co];
    const float* xc = xb + hw;
#pragma unroll 1
    for (int ci = 0; ci < 64; ci += 2) {
        float xv0 = xc[(size_t)ci * HW];
        float xv1 = xc[(size_t)(ci + 1) * HW];
        const float* w0 = &Wsm[ci * 64];
        const float* w1 = &Wsm[(ci + 1) * 64];
#pragma unroll
        for (int co = 0; co < 64; co++) ua[co] = fmaf(w0[co], xv0, ua[co]);
#pragma unroll
        for (int co = 0; co < 64; co++) ua[co] = fmaf(w1[co], xv1, ua[co]);
    }
    float* dst = u1 + (size_t)b * C * HW + hw;
#pragma unroll
    for (int co = 0; co < 64; co++) dst[co * HW] = ua[co];
}

// K6: uf = 5x5 grouped conv (groups=16, 4in/4out) of u1, pad=2
__global__ __launch_bounds__(256) void k6_uf(
        const float* __restrict__ u1, const float* __restrict__ w,
        const float* __restrict__ bias, float* __restrict__ uf) {
    int lane = threadIdx.x & 63, wq = threadIdx.x >> 6;
    int p = blockIdx.x * 64 + lane;
    int b = p / HW, hw = p % HW, h = hw / Ww, w_ = hw % Ww;
    bool interior = (h >= 2 && h < Hh - 2 && w_ >= 2 && w_ < Ww - 2);
#pragma unroll 1
    for (int gi = 0; gi < 4; gi++) {
        int g = wq * 4 + gi;
        float acc[4];
#pragma unroll
        for (int o = 0; o < 4; o++) acc[o] = bias[g * 4 + o];
#pragma unroll 1
        for (int cl = 0; cl < 4; cl++) {
            int ci = g * 4 + cl;
            const float* src = u1 + (size_t)(b * C + ci) * HW;
            float tv[25];
            if (interior) {
#pragma unroll
                for (int kh = 0; kh < 5; kh++)
#pragma unroll
                    for (int kw = 0; kw < 5; kw++)
                        tv[kh * 5 + kw] = src[(h + kh - 2) * Ww + (w_ + kw - 2)];
            } else {
#pragma unroll
                for (int kh = 0; kh < 5; kh++) {
                    int y = h + kh - 2;
#pragma unroll
                    for (int kw = 0; kw < 5; kw++) {
                        int x = w_ + kw - 2;
                        tv[kh * 5 + kw] =
                            ((unsigned)y < (unsigned)Hh && (unsigned)x < (unsigned)Ww)
                                ? src[y * Ww + x] : 0.f;
                    }
                }
            }
#pragma unroll
            for (int o = 0; o < 4; o++) {
                const float* wr = w + ((g * 4 + o) * 4 + cl) * 25;
#pragma unroll
                for (int tp = 0; tp < 25; tp++) acc[o] = fmaf(wr[tp], tv[tp], acc[o]);
            }
        }
        float* dst = uf + (size_t)(b * C + g * 4) * HW + hw;
#pragma unroll
        for (int o = 0; o < 4; o++) dst[o * HW] = acc[o];
    }
}

// helper for K7: load one group's 3x3x4 patch into statically-indexed regs
template <bool INT_>
DEVFN void load_patch(const float* __restrict__ uf, int b, int g, int h, int w,
                      float* u) {
#pragma unroll
    for (int cl = 0; cl < 4; cl++) {
        const float* src = uf + (size_t)(b * C + g * 4 + cl) * HW;
#pragma unroll
        for (int kh = 0; kh < 3; kh++) {
            int y = h + kh - 1;
#pragma unroll
            for (int kw = 0; kw < 3; kw++) {
                int x = w + kw - 1;
                if (INT_)
                    u[cl * 9 + kh * 3 + kw] = src[y * Ww + x];
                else
                    u[cl * 9 + kh * 3 + kw] =
                        ((unsigned)y < (unsigned)Hh && (unsigned)x < (unsigned)Ww)
                            ? src[y * Ww + x] : 0.f;
            }
        }
    }
}

// K7: KBA + ga1 + residual uf + sca scaling -> xmid
// Block = 512 pixels x 1 group; weights in LDS (18.9KB). Dots split into
// even/odd half-chains (4 independent chains per o, NOTE-4); att loads
// software-pipelined one s-iteration ahead.
__global__ __launch_bounds__(256) void k7_kba(
        const float* __restrict__ att, const float* __restrict__ uf,
        const float* __restrict__ kbw, const float* __restrict__ kbb,
        const float* __restrict__ ga1, const float* __restrict__ sca,
        float* __restrict__ xmid) {
    __shared__ float wsm[4608 + 128];
    int bi  = blockIdx.x;              // 0..1599
    int g   = bi / 100;                // 0..15 (uniform)
    int pb  = bi % 100;
    int tid = threadIdx.x;

    for (int e = tid; e < 4608; e += 256) {
        int s = e / 144, r = e - s * 144;
        wsm[e] = kbw[(size_t)s * 2304 + g * 144 + r];
    }
    if (tid < 128) {
        int s = tid >> 2, o = tid & 3;
        wsm[4608 + tid] = kbb[s * 64 + g * 4 + o];
    }
    __syncthreads();

    int pA = pb * 512 + tid;
    int pB = pA + 256;
    int b  = pA / HW;                          // uniform (512 | HW)
    int hwA = pA - b * HW, hwB = pB - b * HW;
    int hA = hwA / Ww, wA = hwA - hA * Ww;
    int hB = hwB / Ww, wB = hwB - hB * Ww;

    float uA[36], uB[36];
    bool intA = (hA >= 1 && hA < Hh - 1 && wA >= 1 && wA < Ww - 1);
    bool intB = (hB >= 1 && hB < Hh - 1 && wB >= 1 && wB < Ww - 1);
    if (intA) load_patch<true>(uf, b, g, hA, wA, uA);
    else      load_patch<false>(uf, b, g, hA, wA, uA);
    if (intB) load_patch<true>(uf, b, g, hB, wB, uB);
    else      load_patch<false>(uf, b, g, hB, wB, uB);

    const float* pAp = att + (size_t)b * NSET * HW + hwA;
    const float* pBp = att + (size_t)b * NSET * HW + hwB;

    float acc0[4] = {0.f, 0.f, 0.f, 0.f}, accb0[4] = {0.f, 0.f, 0.f, 0.f};
    float acc1[4] = {0.f, 0.f, 0.f, 0.f}, accb1[4] = {0.f, 0.f, 0.f, 0.f};

    float a0 = pAp[0], a1 = pBp[0];
#pragma unroll 1
    for (int s = 0; s < 32; s++) {
        int adv = (s < 31) ? HW : 0;       // prefetch next iter's att values
        pAp += adv; pBp += adv;
        float a0n = *pAp, a1n = *pBp;
        const float* wp = &wsm[s * 144];
#pragma unroll
        for (int o = 0; o < 4; o++) {
            const float* wo = wp + o * 36;
            float d0a = wo[0] * uA[0], d0b = wo[1] * uA[1];
            float d1a = wo[0] * uB[0], d1b = wo[1] * uB[1];
#pragma unroll
            for (int i = 2; i < 36; i += 2) {
                d0a = fmaf(wo[i],     uA[i],     d0a);
                d0b = fmaf(wo[i + 1], uA[i + 1], d0b);
                d1a = fmaf(wo[i],     uB[i],     d1a);
                d1b = fmaf(wo[i + 1], uB[i + 1], d1b);
            }
            acc0[o] = fmaf(a0, d0a + d0b, acc0[o]);
            acc1[o] = fmaf(a1, d1a + d1b, acc1[o]);
        }
        const float* kbp = &wsm[4608 + s * 4];
#pragma unroll
        for (int o = 0; o < 4; o++) {
            accb0[o] = fmaf(a0, kbp[o], accb0[o]);
            accb1[o] = fmaf(a1, kbp[o], accb1[o]);
        }
        a0 = a0n; a1 = a1n;
    }

#pragma unroll
    for (int o = 0; o < 4; o++) {
        int co = g * 4 + o;                    // uniform
        float ga = ga1[co];
        float sc = sca[b * 64 + co];
        float ovA = ((acc0[o] + accb0[o]) * ga + uA[o * 9 + 4]) * sc;
        float ovB = ((acc1[o] + accb1[o]) * ga + uB[o * 9 + 4]) * sc;
        xmid[(size_t)(b * C + co) * HW + hwA] = ovA;
        xmid[(size_t)(b * C + co) * HW + hwB] = ovB;
    }
}

// K89: fused conv3+residual (k8) and FFN (k9); y lives in registers.
// Phase-1 LDS: conv3_w TRANSPOSED (16.6KB) -> ci-outer, 64 chains.
// Phase-2 LDS (reuse): w4 + b4 + w5 TRANSPOSED + b5 (49.9KB) for the j-loop.
__global__ __launch_bounds__(256) void k89_ffn(
        const float* __restrict__ xmid, const float* __restrict__ inp,
        const float* __restrict__ conv3w, const float* __restrict__ conv3b,
        const float* __restrict__ beta, const float* __restrict__ lnw,
        const float* __restrict__ lnb, const float* __restrict__ w4,
        const float* __restrict__ b4, const float* __restrict__ w5,
        const float* __restrict__ b5, const float* __restrict__ gamma,
        float* __restrict__ out) {
    __shared__ float Wsm[12480];
    int tid = threadIdx.x;

    // phase 1: W3T[ci*64+co] = conv3w[co*64+ci]; W3b at [4096,4160)
    for (int e = tid; e < 4160; e += 256) {
        float v;
        if (e < 4096) v = conv3w[(e & 63) * 64 + (e >> 6)];
        else          v = conv3b[e - 4096];
        Wsm[e] = v;
    }
    __syncthreads();

    int p = blockIdx.x * 256 + tid;
    int b = p / HW, hw = p % HW;
    const float* xc = xmid + (size_t)b * C * HW + hw;

    float y[64];
#pragma unroll
    for (int co = 0; co < 64; co++) y[co] = Wsm[4096 + co];
#pragma unroll 1
    for (int ci = 0; ci < 64; ci += 2) {
        float xv0 = xc[(size_t)ci * HW];
        float xv1 = xc[(size_t)(ci + 1) * HW];
        const float* w0 = &Wsm[ci * 64];
        const float* w1 = &Wsm[(ci + 1) * 64];
#pragma unroll
        for (int co = 0; co < 64; co++) y[co] = fmaf(w0[co], xv0, y[co]);
#pragma unroll
        for (int co = 0; co < 64; co++) y[co] = fmaf(w1[co], xv1, y[co]);
    }
    const float* ic = inp + (size_t)b * C * HW + hw;
#pragma unroll
    for (int co = 0; co < 64; co++)
        y[co] = ic[(size_t)co * HW] + y[co] * beta[co];

    // phase 2 staging: W4[0,8192) B4[8192,8320) W5T[8320,12416) B5[12416,12480)
    __syncthreads();
    for (int e = tid; e < 12480; e += 256) {
        float v;
        if (e < 8192)       v = w4[e];
        else if (e < 8320)  v = b4[e - 8192];
        else if (e < 12416) { int r = e - 8320; v = w5[(r & 63) * 64 + (r >> 6)]; }
        else                v = b5[e - 12416];
        Wsm[e] = v;
    }
    __syncthreads();

    // LN2
    float s = 0.f, s2 = 0.f;
#pragma unroll
    for (int c = 0; c < 64; c++) { s += y[c]; s2 += y[c] * y[c]; }
    float mu  = s * (1.f / 64.f);
    float var = fmaxf(s2 * (1.f / 64.f) - mu * mu, 0.f);
    float r   = rsqrtf(var + 1e-6f);
    float v[64];
#pragma unroll
    for (int c = 0; c < 64; c++)
        v[c] = (y[c] - mu) * r * lnw[c] + lnb[c];

    float acc[64];
#pragma unroll
    for (int co = 0; co < 64; co++) acc[co] = Wsm[12416 + co];

#pragma unroll 1
    for (int j = 0; j < 64; j++) {
        const float* w1 = &Wsm[j * 64];
        const float* w2 = &Wsm[(64 + j) * 64];
        float t1a = Wsm[8192 + j],      t1b = 0.f;
        float t2a = Wsm[8192 + 64 + j], t2b = 0.f;
#pragma unroll
        for (int ci = 0; ci < 64; ci += 2) {
            t1a = fmaf(w1[ci],     v[ci],     t1a);
            t1b = fmaf(w1[ci + 1], v[ci + 1], t1b);
            t2a = fmaf(w2[ci],     v[ci],     t2a);
            t2b = fmaf(w2[ci + 1], v[ci + 1], t2b);
        }
        float gj = (t1a + t1b) * (t2a + t2b);
        const float* w5c = &Wsm[8320 + j * 64];
#pragma unroll
        for (int co = 0; co < 64; co++)
            acc[co] = fmaf(w5c[co], gj, acc[co]);
    }
    float* oc = out + (size_t)b * C * HW + hw;
#pragma unroll
    for (int co = 0; co < 64; co++)
        oc[(size_t)co * HW] = y[co] + acc[co] * gamma[co];
}

extern "C" void kernel_launch(void* const* d_in, const int* in_sizes, int n_in,
                              void* d_out, int out_size, void* d_ws, size_t ws_size,
                              hipStream_t stream) {
    (void)in_sizes; (void)n_in; (void)out_size; (void)ws_size;

    const float* inp     = (const float*)d_in[0];
    const float* ln1_w   = (const float*)d_in[1];
    const float* ln1_b   = (const float*)d_in[2];
    const float* ln2_w   = (const float*)d_in[3];
    const float* ln2_b   = (const float*)d_in[4];
    const float* sca_w   = (const float*)d_in[5];
    const float* sca_b   = (const float*)d_in[6];
    const float* c11a_w  = (const float*)d_in[7];
    const float* c11a_b  = (const float*)d_in[8];
    const float* c11b_w  = (const float*)d_in[9];
    const float* c11b_b  = (const float*)d_in[10];
    const float* c2a_w   = (const float*)d_in[11];
    const float* c2a_b   = (const float*)d_in[12];
    const float* c2b_w   = (const float*)d_in[13];
    const float* c2b_b   = (const float*)d_in[14];
    const float* conv3_w = (const float*)d_in[15];
    const float* conv3_b = (const float*)d_in[16];
    const float* conv4_w = (const float*)d_in[17];
    const float* conv4_b = (const float*)d_in[18];
    const float* conv5_w = (const float*)d_in[19];
    const float* conv5_b = (const float*)d_in[20];
    const float* kb_w    = (const float*)d_in[21];
    const float* kb_b    = (const float*)d_in[22];
    const float* ga1     = (const float*)d_in[23];
    const float* attg    = (const float*)d_in[24];
    const float* beta    = (const float*)d_in[25];
    const float* gamma   = (const float*)d_in[26];

    // ---- ws arena (~33 MB) ----
    char* ws = (char*)d_ws;
    size_t off = 0;
    auto alloc = [&](size_t bytes) {
        void* r = ws + off;
        off += (bytes + 255) & ~(size_t)255;
        return r;
    };
    float* meanb = (float*)alloc(128 * 4);
    float* scab  = (float*)alloc(128 * 4);
    float* x1    = (float*)alloc((size_t)P * 64 * 4);   // 13.1 MB
    float* attb  = (float*)alloc((size_t)P * 32 * 4);   // 6.55 MB
    float* u1    = (float*)alloc((size_t)P * 64 * 4);   // 13.1 MB
    float* ufb   = x1;   // x1 dead after K45
    float* xmid  = u1;   // u1 dead after K6

    k1_ln1   <<<P / 256, 256, 0, stream>>>(inp, ln1_w, ln1_b, x1);
    k2_mean  <<<B * C, 256, 0, stream>>>(x1, meanb);
    k3_sca   <<<1, 128, 0, stream>>>(sca_w, sca_b, meanb, scab);
    k45_attu <<<P / 256, 256, 0, stream>>>(x1, c2a_w, c2a_b, c2b_w, c2b_b, attg,
                                           c11a_w, c11a_b, attb, u1);
    k6_uf    <<<P / 64, 256, 0, stream>>>(u1, c11b_w, c11b_b, ufb);
    k7_kba   <<<1600, 256, 0, stream>>>(attb, ufb, kb_w, kb_b, ga1, scab, xmid);
    k89_ffn  <<<P / 256, 256, 0, stream>>>(xmid, inp, conv3_w, conv3_b, beta,
                                           ln2_w, ln2_b, conv4_w, conv4_b,
                                           conv5_w, conv5_b, gamma, (float*)d_out);
}